// Round 4
// baseline (153.573 us; speedup 1.0000x reference)
//
#include <hip/hip_runtime.h>
#include <hip/hip_cooperative_groups.h>

namespace cg = cooperative_groups;

// out[n,co] = (1/1225) * sum_ci Sx[n,ci] * Sw[co,ci] + bias[co]     (exact, absmax 0.0 in R2/R3)
//   Sx[n,ci]  = sum over 32x32 spatial of x[n,ci]
//   swt[ci,co] = tapsum(w[co,ci,:,:])
//
// Single cooperative kernel: 1024 blocks x 256 threads, __launch_bounds__(256,4)
// -> 4 blocks/CU x 256 CU = 1024 co-resident (exact fit).

__global__ __launch_bounds__(256, 4) void k_all(const float* __restrict__ x,
                                                const float* __restrict__ w,
                                                const float* __restrict__ bias,
                                                float* __restrict__ sx,
                                                float* __restrict__ swt,
                                                float* __restrict__ out) {
    const int b    = blockIdx.x;
    const int tid  = threadIdx.x;
    const int lane = tid & 63;
    const int wid  = tid >> 6;
    __shared__ float ws4[4][8];

    // ---- Phase A: x spatial sums. 16 rows/block, 2 passes of 8 rows. ----
    #pragma unroll
    for (int pass = 0; pass < 2; ++pass) {
        const int row0 = b * 16 + pass * 8;
        const float4* p = reinterpret_cast<const float4*>(x + (size_t)row0 * 1024);
        float s[8];
        #pragma unroll
        for (int r = 0; r < 8; ++r) {            // 8 independent loads in flight
            const float4 v = p[r * 256 + tid];
            s[r] = v.x + v.y + v.z + v.w;
        }
        #pragma unroll
        for (int o = 32; o >= 1; o >>= 1) {
            #pragma unroll
            for (int r = 0; r < 8; ++r) s[r] += __shfl_xor(s[r], o, 64);
        }
        if (pass) __syncthreads();               // protect ws4 reuse
        if (lane == 0) {
            #pragma unroll
            for (int r = 0; r < 8; ++r) ws4[wid][r] = s[r];
        }
        __syncthreads();
        if (tid < 8)
            sx[row0 + tid] = ws4[0][tid] + ws4[1][tid] + ws4[2][tid] + ws4[3][tid];
    }

    // ---- Phase B (blocks 768..1023): w tap-sums, stored transposed. ----
    if (b >= 768) {
        const int d0 = b - 768;                  // weight dim0 (= co)
        const int d1 = tid;                      // weight dim1 (= ci)
        const float4* p = reinterpret_cast<const float4*>(w + ((size_t)d0 * 256 + d1) * 16);
        float s = 0.f;
        #pragma unroll
        for (int k = 0; k < 4; ++k) {
            const float4 v = p[k];
            s += v.x + v.y + v.z + v.w;
        }
        swt[(size_t)d1 * 256 + d0] = s;          // swt[ci*256+co] = tapsum(w[co,ci])
    }

    // ---- Phase C (block 0): init out with bias (rewritten every call). ----
    if (b == 0) {
        const float bv = bias[tid];
        #pragma unroll
        for (int n = 0; n < 64; ++n) out[n * 256 + tid] = bv;
    }

    cg::this_grid().sync();

    // ---- Phase D (blocks 0..255): gemm partials over 64 ci each, atomicAdd. ----
    if (b < 256) {
        const int n  = b >> 2;
        const int q  = b & 3;                    // ci range [64q, 64q+64)
        const int co = tid;
        const float* sxn = sx + n * 256 + q * 64;
        const float* swp = swt + (size_t)(q * 64) * 256 + co;
        float acc = 0.f;
        #pragma unroll 8
        for (int i = 0; i < 64; ++i) acc += sxn[i] * swp[i * 256];
        atomicAdd(out + n * 256 + co, acc * (1.0f / 1225.0f));
    }
}

extern "C" void kernel_launch(void* const* d_in, const int* in_sizes, int n_in,
                              void* d_out, int out_size, void* d_ws, size_t ws_size,
                              hipStream_t stream) {
    const float* x    = (const float*)d_in[0];  // [64,256,32,32]
    const float* w    = (const float*)d_in[1];  // [256,256,4,4]
    const float* bias = (const float*)d_in[2];  // [256]
    float* out = (float*)d_out;                 // [64,256] fp32

    float* sx  = (float*)d_ws;                  // 64*256 floats
    float* swt = sx + 64 * 256;                 // 256*256 floats

    void* args[] = {(void*)&x, (void*)&w, (void*)&bias,
                    (void*)&sx, (void*)&swt, (void*)&out};
    hipLaunchCooperativeKernel((const void*)k_all, dim3(1024), dim3(256),
                               args, 0, stream);
}

// Round 5
// 20.686 us; speedup vs baseline: 7.4239x; 7.4239x over previous
//
#include <hip/hip_runtime.h>

// out[n,co] = (1/1225) * sum_ci Sx[n,ci] * Sw[co,ci] + bias[co]   (exact; absmax 0.0 R2/R3)
//   Sx[n,ci]   = sum over 32x32 spatial of x[n,ci]
//   swt[ci,co] = tapsum(w[co,ci,:,:])   (stored transposed for coalesced gemm reads)

#define XBLOCKS 2048   // 16384 rows / 8 rows per block

// ---- Node 1: blocks [0,2048) reduce x (8 rows each, 8 loads in flight);
//      blocks [2048,2304) reduce w (one d0 row each, stored transposed). ----
__global__ __launch_bounds__(256) void k_reduce(const float* __restrict__ x,
                                                const float* __restrict__ w,
                                                float* __restrict__ sx,
                                                float* __restrict__ swt) {
    const int b   = blockIdx.x;
    const int tid = threadIdx.x;
    if (b < XBLOCKS) {
        const int row0 = b * 8;  // n*256+c base
        const float4* p = reinterpret_cast<const float4*>(x + (size_t)row0 * 1024);
        float s[8];
        #pragma unroll
        for (int r = 0; r < 8; ++r) {           // 8 independent float4 loads in flight
            const float4 v = p[r * 256 + tid];
            s[r] = v.x + v.y + v.z + v.w;
        }
        #pragma unroll
        for (int o = 32; o >= 1; o >>= 1) {
            #pragma unroll
            for (int r = 0; r < 8; ++r) s[r] += __shfl_xor(s[r], o, 64);
        }
        __shared__ float ws4[4][8];             // [wave][row]
        const int lane = tid & 63;
        const int wid  = tid >> 6;
        if (lane == 0) {
            #pragma unroll
            for (int r = 0; r < 8; ++r) ws4[wid][r] = s[r];
        }
        __syncthreads();
        if (tid < 8)
            sx[row0 + tid] = ws4[0][tid] + ws4[1][tid] + ws4[2][tid] + ws4[3][tid];
    } else {
        const int d0 = b - XBLOCKS;             // weight dim0 (= co)
        const int d1 = tid;                     // weight dim1 (= ci)
        const float4* p = reinterpret_cast<const float4*>(w + ((size_t)d0 * 256 + d1) * 16);
        float s = 0.f;
        #pragma unroll
        for (int k = 0; k < 4; ++k) {
            const float4 v = p[k];
            s += v.x + v.y + v.z + v.w;
        }
        swt[(size_t)d1 * 256 + d0] = s;         // swt[ci*256+co] = tapsum(w[co,ci])
    }
}

// ---- Node 2: 256 blocks = (n, co-chunk of 64). Each thread: 64-ci partial dot;
//      4-way LDS combine. out[n,co] = acc/1225 + bias[co]. ----
__global__ __launch_bounds__(256) void k_gemm(const float* __restrict__ sx,
                                              const float* __restrict__ swt,
                                              const float* __restrict__ bias,
                                              float* __restrict__ out) {
    const int b     = blockIdx.x;   // 256
    const int n     = b >> 2;
    const int chunk = b & 3;
    const int tid   = threadIdx.x;
    const int q     = tid >> 6;     // ci quarter
    const int col   = tid & 63;
    const int co    = chunk * 64 + col;

    __shared__ float sxr[256];
    sxr[tid] = sx[n * 256 + tid];
    __syncthreads();

    const float* swp = swt + (size_t)(q * 64) * 256 + co;
    const float* sxp = sxr + q * 64;
    float acc = 0.f;
    #pragma unroll 8
    for (int i = 0; i < 64; ++i) acc += sxp[i] * swp[(size_t)i * 256];

    __shared__ float red[4][64];
    red[q][col] = acc;
    __syncthreads();
    if (tid < 64) {
        const float r = red[0][tid] + red[1][tid] + red[2][tid] + red[3][tid];
        out[n * 256 + chunk * 64 + tid] = r * (1.0f / 1225.0f) + bias[chunk * 64 + tid];
    }
}

extern "C" void kernel_launch(void* const* d_in, const int* in_sizes, int n_in,
                              void* d_out, int out_size, void* d_ws, size_t ws_size,
                              hipStream_t stream) {
    const float* x    = (const float*)d_in[0];  // [64,256,32,32]
    const float* w    = (const float*)d_in[1];  // [256,256,4,4]
    const float* bias = (const float*)d_in[2];  // [256]
    float* out = (float*)d_out;                 // [64,256,1,1] fp32

    float* sx  = (float*)d_ws;                  // 64*256 floats
    float* swt = sx + 64 * 256;                 // 256*256 floats

    k_reduce<<<XBLOCKS + 256, 256, 0, stream>>>(x, w, sx, swt);
    k_gemm<<<256, 256, 0, stream>>>(sx, swt, bias, out);
}